// Round 5
// baseline (705.898 us; speedup 1.0000x reference)
//
#include <hip/hip_runtime.h>
#include <hip/hip_bf16.h>

typedef __attribute__((ext_vector_type(8))) __bf16 bf16x8;
typedef __attribute__((ext_vector_type(4))) __bf16 bf16x4;
typedef __attribute__((ext_vector_type(4))) float f32x4;
typedef __attribute__((ext_vector_type(16))) float f32x16;

#define MFMA16(a, b, c) __builtin_amdgcn_mfma_f32_16x16x32_bf16((a), (b), (c), 0, 0, 0)
#define MFMA32(a, b, c) __builtin_amdgcn_mfma_f32_32x32x16_bf16((a), (b), (c), 0, 0, 0)

// ---------------------------------------------------------------------------
// fp32 -> bf16 elementwise convert
// ---------------------------------------------------------------------------
__global__ __launch_bounds__(256) void k_conv(const float* __restrict__ src,
                                              __bf16* __restrict__ dst, long n4) {
  long i = (long)blockIdx.x * 256 + threadIdx.x;
  if (i >= n4) return;
  float4 v = ((const float4*)src)[i];
  bf16x4 o;
  o[0] = (__bf16)v.x; o[1] = (__bf16)v.y; o[2] = (__bf16)v.z; o[3] = (__bf16)v.w;
  ((bf16x4*)dst)[i] = o;
}

// ---------------------------------------------------------------------------
// fp32 [R][C] -> bf16 [C][R] transpose-convert
// ---------------------------------------------------------------------------
__global__ __launch_bounds__(256) void k_transpose_f32_bf16(
    const float* __restrict__ src, __bf16* __restrict__ dst, int R, int C) {
  __shared__ float tl[64][68];
  int tid = threadIdx.x;
  int r0 = blockIdx.y * 64, c0 = blockIdx.x * 64;
#pragma unroll
  for (int j = 0; j < 4; ++j) {
    int idx = j * 256 + tid;
    int row = idx >> 4, q4 = (idx & 15) * 4;
    float4 v = *(const float4*)(src + (size_t)(r0 + row) * C + c0 + q4);
    tl[row][q4 + 0] = v.x; tl[row][q4 + 1] = v.y;
    tl[row][q4 + 2] = v.z; tl[row][q4 + 3] = v.w;
  }
  __syncthreads();
#pragma unroll
  for (int j = 0; j < 2; ++j) {
    int idx = j * 256 + tid;
    int orow = idx >> 3, ch = (idx & 7) * 8;
    bf16x8 pk;
#pragma unroll
    for (int e = 0; e < 8; ++e) pk[e] = (__bf16)tl[ch + e][orow];
    *(bf16x8*)(dst + (size_t)(c0 + orow) * R + r0 + ch) = pk;
  }
}

// ---------------------------------------------------------------------------
// V slice of qkv -> Vt[pair][d][s]
// ---------------------------------------------------------------------------
__global__ __launch_bounds__(256) void k_transpose_v(
    const __bf16* __restrict__ qkv, __bf16* __restrict__ vt) {
  __shared__ __bf16 tl[64][72];
  int tid = threadIdx.x;
  int p = blockIdx.z, b = p >> 3, h = p & 7;
  int d0 = blockIdx.x * 64, s0 = blockIdx.y * 64;
  const __bf16* src = qkv + (size_t)b * 1024 * 12288 + 8192 + h * 512;
#pragma unroll
  for (int j = 0; j < 2; ++j) {
    int idx = j * 256 + tid;
    int row = idx >> 3, ch = (idx & 7) * 8;
    bf16x8 v = *(const bf16x8*)(src + (size_t)(s0 + row) * 12288 + d0 + ch);
#pragma unroll
    for (int e = 0; e < 8; ++e) tl[row][ch + e] = v[e];
  }
  __syncthreads();
#pragma unroll
  for (int j = 0; j < 2; ++j) {
    int idx = j * 256 + tid;
    int orow = idx >> 3, ch = (idx & 7) * 8;
    bf16x8 pk;
#pragma unroll
    for (int e = 0; e < 8; ++e) pk[e] = tl[ch + e][orow];
    *(bf16x8*)(vt + (size_t)p * 524288 + (size_t)(d0 + orow) * 1024 + s0 + ch) = pk;
  }
}

// ---------------------------------------------------------------------------
// Shared 8-phase machinery (both GEMM kernels).
// LDS 128KB: A[2buf][2half][64r][64k]-per-wm + B[2buf][2half][128n][64k].
// ---------------------------------------------------------------------------
#define BARRIER() __builtin_amdgcn_s_barrier()
#define VMC6() asm volatile("s_waitcnt vmcnt(6)" ::: "memory")
#define WAITDS()                                     \
  do {                                               \
    asm volatile("s_waitcnt lgkmcnt(0)" ::: "memory"); \
    __builtin_amdgcn_sched_barrier(0);               \
  } while (0)

#define STAGE_A(mh, tau)                                                      \
  do {                                                                        \
    int tc = (tau) < NT ? (tau) : NT - 1;                                     \
    char* dbase = ldsB + ((tau)&1) * 32768 + (mh)*16384;                      \
    _Pragma("unroll") for (int i = 0; i < 2; ++i)                             \
        __builtin_amdgcn_global_load_lds(                                     \
            (const __attribute__((address_space(1))) void*)(Ap +              \
                offA[i][mh] + tc * 64),                                       \
            (__attribute__((address_space(3))) void*)(dbase +                 \
                (i * 512 + w * 64) * 16), 16, 0, 0);                          \
  } while (0)

#define STAGE_B(nh, tau)                                                      \
  do {                                                                        \
    int tc = (tau) < NT ? (tau) : NT - 1;                                     \
    char* dbase = ldsB + 65536 + ((tau)&1) * 32768 + (nh)*16384;              \
    _Pragma("unroll") for (int i = 0; i < 2; ++i)                             \
        __builtin_amdgcn_global_load_lds(                                     \
            (const __attribute__((address_space(1))) void*)(Bp +              \
                offB[i][nh] + tc * 64),                                       \
            (__attribute__((address_space(3))) void*)(dbase +                 \
                (i * 512 + w * 64) * 16), 16, 0, 0);                          \
  } while (0)

// ---- 16x16x32 fragment macros (attention pair-GEMMs, modes 2/3) -----------
#define LDA(buf, mh)                                                          \
  do {                                                                        \
    _Pragma("unroll") for (int mi = 0; mi < 4; ++mi) {                        \
      int r = wm * 64 + mi * 16 + r16;                                        \
      _Pragma("unroll") for (int ks = 0; ks < 2; ++ks) {                      \
        int gg = ks * 4 + g;                                                  \
        af[mi][ks] = *(const bf16x8*)(ldsB + (buf)*32768 + (mh)*16384 +       \
                                      r * 128 + ((gg ^ (r & 7)) << 4));       \
      }                                                                       \
    }                                                                         \
  } while (0)

#define LDB(buf, nh, BQ)                                                      \
  do {                                                                        \
    _Pragma("unroll") for (int ni = 0; ni < 2; ++ni) {                        \
      int r = wn * 32 + ni * 16 + r16;                                        \
      _Pragma("unroll") for (int ks = 0; ks < 2; ++ks) {                      \
        int gg = ks * 4 + g;                                                  \
        BQ[ni][ks] = *(const bf16x8*)(ldsB + 65536 + (buf)*32768 +            \
                                      (nh)*16384 + r * 128 +                  \
                                      ((gg ^ (r & 7)) << 4));                 \
      }                                                                       \
    }                                                                         \
  } while (0)

#define QUAD(mh, nh, BQ)                                                      \
  do {                                                                        \
    __builtin_amdgcn_s_setprio(1);                                            \
    _Pragma("unroll") for (int ks = 0; ks < 2; ++ks)                          \
        _Pragma("unroll") for (int mi = 0; mi < 4; ++mi)                      \
            _Pragma("unroll") for (int ni = 0; ni < 2; ++ni)                  \
                acc[(mh)*4 + mi][(nh)*2 + ni] =                               \
                    MFMA16(af[mi][ks], BQ[ni][ks],                            \
                           acc[(mh)*4 + mi][(nh)*2 + ni]);                    \
    __builtin_amdgcn_s_setprio(0);                                            \
    __builtin_amdgcn_sched_barrier(0);                                        \
  } while (0)

// ---- 32x32x16 fragment macros (big GEMMs, modes 0/1) ----------------------
// A-frag: row = lane&31, k = (lane>>5)*8 + e; B-frag symmetric.
#define LDA32(buf, mh)                                                        \
  do {                                                                        \
    _Pragma("unroll") for (int mt = 0; mt < 2; ++mt) {                        \
      int u = wm * 64 + mt * 32 + l31;                                        \
      _Pragma("unroll") for (int ks = 0; ks < 4; ++ks) {                      \
        int slot = ks * 2 + c2;                                               \
        af32[mt][ks] = *(const bf16x8*)(ldsB + (buf)*32768 + (mh)*16384 +     \
                                        u * 128 + ((slot ^ (u & 7)) << 4));   \
      }                                                                       \
    }                                                                         \
  } while (0)

#define LDB32(buf, nh, BQ)                                                    \
  do {                                                                        \
    int u = wn * 32 + l31;                                                    \
    _Pragma("unroll") for (int ks = 0; ks < 4; ++ks) {                        \
      int slot = ks * 2 + c2;                                                 \
      BQ[ks] = *(const bf16x8*)(ldsB + 65536 + (buf)*32768 + (nh)*16384 +     \
                                u * 128 + ((slot ^ (u & 7)) << 4));           \
    }                                                                         \
  } while (0)

#define QUAD32(mh, nh, BQ)                                                    \
  do {                                                                        \
    __builtin_amdgcn_s_setprio(1);                                            \
    _Pragma("unroll") for (int ks = 0; ks < 4; ++ks)                          \
        _Pragma("unroll") for (int mt = 0; mt < 2; ++mt)                      \
            acc32[(mh)*2 + mt][nh] =                                          \
                MFMA32(af32[mt][ks], BQ[ks], acc32[(mh)*2 + mt][nh]);         \
    __builtin_amdgcn_s_setprio(0);                                            \
    __builtin_amdgcn_sched_barrier(0);                                        \
  } while (0)

#define PHASE_LOOP(LDA_, LDB_, QUAD_)                                         \
  for (int it = 0; it < NI; ++it) {                                           \
    int t0 = 2 * it;                                                          \
    LDA_(0, 0); LDB_(0, 0, bq0);                                              \
    STAGE_B(0, t0 + 1);                                                       \
    BARRIER(); WAITDS(); QUAD_(0, 0, bq0); BARRIER();                         \
    LDB_(0, 1, bq1);                                                          \
    STAGE_A(0, t0 + 2);                                                       \
    BARRIER(); WAITDS(); QUAD_(0, 1, bq1); BARRIER();                         \
    LDA_(0, 1);                                                               \
    STAGE_B(1, t0 + 2);                                                       \
    BARRIER(); WAITDS(); QUAD_(1, 1, bq1); BARRIER();                         \
    STAGE_A(1, t0 + 2);                                                       \
    VMC6();                                                                   \
    BARRIER(); WAITDS(); QUAD_(1, 0, bq0); BARRIER();                         \
    LDA_(1, 0); LDB_(1, 0, bq0);                                              \
    STAGE_B(0, t0 + 2);                                                       \
    BARRIER(); WAITDS(); QUAD_(0, 0, bq0); BARRIER();                         \
    LDB_(1, 1, bq1);                                                          \
    STAGE_A(0, t0 + 3);                                                       \
    BARRIER(); WAITDS(); QUAD_(0, 1, bq1); BARRIER();                         \
    LDA_(1, 1);                                                               \
    STAGE_B(1, t0 + 3);                                                       \
    BARRIER(); WAITDS(); QUAD_(1, 1, bq1); BARRIER();                         \
    STAGE_A(1, t0 + 3);                                                       \
    VMC6();                                                                   \
    BARRIER(); WAITDS(); QUAD_(1, 0, bq0); BARRIER();                         \
  }

#define SETUP_OFFSETS()                                                       \
  int offA[2][2], offB[2][2];                                                 \
  _Pragma("unroll") for (int i = 0; i < 2; ++i) {                             \
    int c = i * 512 + tid;                                                    \
    int r = c >> 3, slot = c & 7;                                             \
    int colsw = (slot ^ (r & 7)) << 3;                                        \
    _Pragma("unroll") for (int h = 0; h < 2; ++h) {                           \
      int RA = (r >> 6) * 128 + h * 64 + (r & 63);                            \
      int RB = (r >> 5) * 64 + h * 32 + (r & 31);                             \
      offA[i][h] = RA * lda + colsw;                                          \
      offB[i][h] = RB * ldb + colsw;                                          \
    }                                                                         \
  }

#define PROLOGUE()                                                            \
  STAGE_A(0, 0); STAGE_B(1, 0); STAGE_A(1, 0); STAGE_B(0, 0);                 \
  STAGE_A(0, 1); STAGE_B(1, 1); STAGE_A(1, 1);                                \
  VMC6();                                                                     \
  BARRIER();

// ---------------------------------------------------------------------------
// Big GEMMs (32x32x16): MODE 0 = bf16 out; MODE 1 = fp32 out + bias.
// 2D XCD rectangles (4x2), column-major walk within each rect.
// ---------------------------------------------------------------------------
template <int MODE>
__global__ __launch_bounds__(512, 2) void k_gemm8w(
    const __bf16* __restrict__ Abase, const __bf16* __restrict__ Bbase,
    void* __restrict__ Cout, const float* __restrict__ aux,
    int lda, int ldb, int N, int K) {
  __shared__ __align__(128) __bf16 lds[65536];
  char* ldsB = (char*)lds;
  int tid = threadIdx.x;
  int w = tid >> 6, lane = tid & 63;
  int l31 = lane & 31, c2 = lane >> 5;
  int wm = w >> 2, wn = w & 3;

  // XCD-rect swizzle: 8 XCDs as 4x2 rectangles, column-major (by-fast) walk.
  int gx = gridDim.x, gy = gridDim.y;
  int RX = gx >> 2, RY = gy >> 1;
  int orig = blockIdx.y * gx + blockIdx.x;
  int xcd = orig & 7, idx = orig >> 3;
  int lbx = idx / RY, lby = idx - lbx * RY;
  int bx = (xcd & 3) * RX + lbx;
  int by = (xcd >> 2) * RY + lby;
  int m0 = by * 256, n0 = bx * 256;

  const __bf16* Ap = Abase + (size_t)m0 * lda;
  const __bf16* Bp = Bbase + (size_t)n0 * ldb;
  SETUP_OFFSETS()

  int NT = K >> 6, NI = K >> 7;
  f32x16 acc32[4][2];
#pragma unroll
  for (int a = 0; a < 4; ++a)
#pragma unroll
    for (int bq = 0; bq < 2; ++bq)
#pragma unroll
      for (int e = 0; e < 16; ++e) acc32[a][bq][e] = 0.f;
  bf16x8 af32[2][4], bq0[4], bq1[4];

  PROLOGUE()
  PHASE_LOOP(LDA32, LDB32, QUAD32)

  // epilogue: 32x32 C/D layout col=lane&31, row=(reg&3)+8*(reg>>2)+4*(lane>>5)
#pragma unroll
  for (int mt4 = 0; mt4 < 4; ++mt4) {
#pragma unroll
    for (int nh = 0; nh < 2; ++nh) {
      int col = n0 + wn * 64 + nh * 32 + l31;
#pragma unroll
      for (int reg = 0; reg < 16; ++reg) {
        int row = m0 + wm * 128 + mt4 * 32 + (reg & 3) + 8 * (reg >> 2) + 4 * c2;
        float v = acc32[mt4][nh][reg];
        if (MODE == 0) {
          ((__bf16*)Cout)[(size_t)row * N + col] = (__bf16)v;
        } else {
          ((float*)Cout)[(size_t)row * N + col] = v + aux[col];
        }
      }
    }
  }
}

// ---------------------------------------------------------------------------
// Attention pair-GEMMs (16x16x32): MODE 2 = exp(acc/64)->P + Lpart;
// MODE 3 = acc/sum(Lpart) -> attnO scatter.
// ---------------------------------------------------------------------------
template <int MODE>
__global__ __launch_bounds__(512, 2) void k_gemm8(
    const __bf16* __restrict__ Abase, const __bf16* __restrict__ Bbase,
    void* __restrict__ Cout, const float* __restrict__ aux,
    int lda, int ldb, int N, int K) {
  __shared__ __align__(128) __bf16 lds[65536];
  char* ldsB = (char*)lds;
  int tid = threadIdx.x;
  int w = tid >> 6, lane = tid & 63;
  int r16 = lane & 15, g = lane >> 4;
  int wm = w >> 2, wn = w & 3;
  int z = blockIdx.z;

  int bx = blockIdx.x, by = blockIdx.y;
  int m0 = by * 256, n0 = bx * 256;

  const __bf16 *Ap, *Bp;
  if (MODE == 2) {
    int b = z >> 3, h = z & 7;
    Ap = Abase + (size_t)b * 1024 * 12288 + h * 512;          // Q rows
    Bp = Abase + (size_t)b * 1024 * 12288 + 4096 + h * 512;   // K rows
  } else {
    Ap = Abase + (size_t)z * 1048576;   // P[z]
    Bp = Bbase + (size_t)z * 524288;    // Vt[z]
  }
  Ap += (size_t)m0 * lda;
  Bp += (size_t)n0 * ldb;
  SETUP_OFFSETS()

  int NT = K >> 6, NI = K >> 7;
  f32x4 acc[8][4];
#pragma unroll
  for (int a = 0; a < 8; ++a)
#pragma unroll
    for (int bq = 0; bq < 4; ++bq) acc[a][bq] = f32x4{0.f, 0.f, 0.f, 0.f};
  bf16x8 af[4][2], bq0[2][2], bq1[2][2];

  PROLOGUE()
  PHASE_LOOP(LDA, LDB, QUAD)

  if (MODE == 2) {
    asm volatile("s_waitcnt vmcnt(0)" ::: "memory");
    __syncthreads();
    float* Lbuf = (float*)ldsB;
#pragma unroll
    for (int mig = 0; mig < 8; ++mig) {
#pragma unroll
      for (int ii = 0; ii < 4; ++ii) {
        int row = m0 + wm * 128 + mig * 16 + g * 4 + ii;
        float s = 0.f;
#pragma unroll
        for (int nig = 0; nig < 4; ++nig) {
          int col = n0 + wn * 64 + nig * 16 + r16;
          float e = __expf(acc[mig][nig][ii] * 0.015625f);
          ((__bf16*)Cout)[(size_t)z * 1048576 + (size_t)row * 1024 + col] =
              (__bf16)e;
          s += e;
        }
        s += __shfl_xor(s, 1, 64);
        s += __shfl_xor(s, 2, 64);
        s += __shfl_xor(s, 4, 64);
        s += __shfl_xor(s, 8, 64);
        if (r16 == 0)
          Lbuf[(wm * 4 + wn) * 128 + mig * 16 + g * 4 + ii] = s;
      }
    }
    __syncthreads();
    if (tid < 256) {
      int wmi = tid >> 7, rl = tid & 127;
      const float* base = Lbuf + wmi * 512;
      float s = base[rl] + base[128 + rl] + base[256 + rl] + base[384 + rl];
      ((float*)aux)[z * 4096 + blockIdx.x * 1024 + m0 + tid] = s;
    }
    return;
  }

#pragma unroll
  for (int mig = 0; mig < 8; ++mig) {
#pragma unroll
    for (int ii = 0; ii < 4; ++ii) {
      int row = m0 + wm * 128 + mig * 16 + g * 4 + ii;
      float lval = aux[z * 4096 + row] + aux[z * 4096 + 1024 + row] +
                   aux[z * 4096 + 2048 + row] + aux[z * 4096 + 3072 + row];
#pragma unroll
      for (int nig = 0; nig < 4; ++nig) {
        int col = n0 + wn * 64 + nig * 16 + r16;
        float v = acc[mig][nig][ii];
        ((__bf16*)Cout)[(size_t)((z >> 3) * 1024 + row) * 4096 +
                        (z & 7) * 512 + col] = (__bf16)(v / lval);
      }
    }
  }
}

// ---------------------------------------------------------------------------
// Orchestration. ws layout (268.4 MB):
//   [0,        33.5MB)  xb  (x bf16)  -> reused as attnO
//   [33.5MB,  134.2MB)  wT (WqkvT)    -> reused as P(64MB)+Lpart, then WoutT
//   [134.2MB, 234.9MB)  qkv
//   [234.9MB, 268.4MB)  vt
// ---------------------------------------------------------------------------
extern "C" void kernel_launch(void* const* d_in, const int* in_sizes, int n_in,
                              void* d_out, int out_size, void* d_ws, size_t ws_size,
                              hipStream_t stream) {
  const float* x = (const float*)d_in[0];
  const float* Wqkv = (const float*)d_in[1];
  const float* Wout = (const float*)d_in[2];
  const float* bout = (const float*)d_in[3];
  float* out = (float*)d_out;
  char* ws = (char*)d_ws;

  __bf16* xb = (__bf16*)(ws);
  __bf16* wT = (__bf16*)(ws + 33554432);
  __bf16* P = (__bf16*)(ws + 33554432);
  float* Lpart = (float*)(ws + 33554432 + 67108864);  // [32][4][1024]
  __bf16* qkv = (__bf16*)(ws + 134217728);
  __bf16* vt = (__bf16*)(ws + 234881024);

  k_conv<<<16384, 256, 0, stream>>>(x, xb, 4194304);
  k_transpose_f32_bf16<<<dim3(192, 64), 256, 0, stream>>>(Wqkv, wT, 4096, 12288);
  // qkv = xb @ Wqkv : M=4096 N=12288 K=4096 -> 48x16 blocks
  k_gemm8w<0><<<dim3(48, 16), 512, 0, stream>>>(xb, wT, qkv, nullptr, 4096, 4096, 12288, 4096);
  k_transpose_v<<<dim3(8, 16, 32), 256, 0, stream>>>(qkv, vt);
  // P = exp(scale * Q K^T) + Lpart : per pair M=N=1024 K=512
  k_gemm8<2><<<dim3(4, 4, 32), 512, 0, stream>>>(qkv, qkv, P, Lpart, 12288, 12288, 1024, 512);
  // attnO = (P @ V) / L : per pair M=1024 N=512 K=1024
  k_gemm8<3><<<dim3(2, 4, 32), 512, 0, stream>>>(P, vt, xb, Lpart, 1024, 1024, 512, 1024);
  k_transpose_f32_bf16<<<dim3(64, 64), 256, 0, stream>>>(Wout, wT, 4096, 4096);
  // out = attnO @ Wout + bout : M=N=4096 K=4096 -> 16x16 blocks
  k_gemm8w<1><<<dim3(16, 16), 512, 0, stream>>>(xb, wT, out, bout, 4096, 4096, 4096, 4096);
}

// Round 6
// 647.093 us; speedup vs baseline: 1.0909x; 1.0909x over previous
//
#include <hip/hip_runtime.h>
#include <hip/hip_bf16.h>

typedef __attribute__((ext_vector_type(8))) __bf16 bf16x8;
typedef __attribute__((ext_vector_type(4))) __bf16 bf16x4;
typedef __attribute__((ext_vector_type(4))) float f32x4;

#define MFMA16(a, b, c) __builtin_amdgcn_mfma_f32_16x16x32_bf16((a), (b), (c), 0, 0, 0)

// ---------------------------------------------------------------------------
// fp32 -> bf16 elementwise convert
// ---------------------------------------------------------------------------
__global__ __launch_bounds__(256) void k_conv(const float* __restrict__ src,
                                              __bf16* __restrict__ dst, long n4) {
  long i = (long)blockIdx.x * 256 + threadIdx.x;
  if (i >= n4) return;
  float4 v = ((const float4*)src)[i];
  bf16x4 o;
  o[0] = (__bf16)v.x; o[1] = (__bf16)v.y; o[2] = (__bf16)v.z; o[3] = (__bf16)v.w;
  ((bf16x4*)dst)[i] = o;
}

// ---------------------------------------------------------------------------
// fp32 [R][C] -> bf16 [C][R] transpose-convert
// ---------------------------------------------------------------------------
__global__ __launch_bounds__(256) void k_transpose_f32_bf16(
    const float* __restrict__ src, __bf16* __restrict__ dst, int R, int C) {
  __shared__ float tl[64][68];
  int tid = threadIdx.x;
  int r0 = blockIdx.y * 64, c0 = blockIdx.x * 64;
#pragma unroll
  for (int j = 0; j < 4; ++j) {
    int idx = j * 256 + tid;
    int row = idx >> 4, q4 = (idx & 15) * 4;
    float4 v = *(const float4*)(src + (size_t)(r0 + row) * C + c0 + q4);
    tl[row][q4 + 0] = v.x; tl[row][q4 + 1] = v.y;
    tl[row][q4 + 2] = v.z; tl[row][q4 + 3] = v.w;
  }
  __syncthreads();
#pragma unroll
  for (int j = 0; j < 2; ++j) {
    int idx = j * 256 + tid;
    int orow = idx >> 3, ch = (idx & 7) * 8;
    bf16x8 pk;
#pragma unroll
    for (int e = 0; e < 8; ++e) pk[e] = (__bf16)tl[ch + e][orow];
    *(bf16x8*)(dst + (size_t)(c0 + orow) * R + r0 + ch) = pk;
  }
}

// ---------------------------------------------------------------------------
// V slice of qkv -> Vt[pair][d][s]
// ---------------------------------------------------------------------------
__global__ __launch_bounds__(256) void k_transpose_v(
    const __bf16* __restrict__ qkv, __bf16* __restrict__ vt) {
  __shared__ __bf16 tl[64][72];
  int tid = threadIdx.x;
  int p = blockIdx.z, b = p >> 3, h = p & 7;
  int d0 = blockIdx.x * 64, s0 = blockIdx.y * 64;
  const __bf16* src = qkv + (size_t)b * 1024 * 12288 + 8192 + h * 512;
#pragma unroll
  for (int j = 0; j < 2; ++j) {
    int idx = j * 256 + tid;
    int row = idx >> 3, ch = (idx & 7) * 8;
    bf16x8 v = *(const bf16x8*)(src + (size_t)(s0 + row) * 12288 + d0 + ch);
#pragma unroll
    for (int e = 0; e < 8; ++e) tl[row][ch + e] = v[e];
  }
  __syncthreads();
#pragma unroll
  for (int j = 0; j < 2; ++j) {
    int idx = j * 256 + tid;
    int orow = idx >> 3, ch = (idx & 7) * 8;
    bf16x8 pk;
#pragma unroll
    for (int e = 0; e < 8; ++e) pk[e] = tl[ch + e][orow];
    *(bf16x8*)(vt + (size_t)p * 524288 + (size_t)(d0 + orow) * 1024 + s0 + ch) = pk;
  }
}

// ---------------------------------------------------------------------------
// 256x256 8-phase GEMM, 16x16x32 fragments, PIPELINED ds_reads (one phase
// ahead) with counted lgkm waits. 512 thr = 8 waves (2Mx4N), acc[8][4].
// Register sets: afE/afO (A half 0/1 of current tile), bqE/bqO (B half 0/1).
// Issue schedule per tile t (buf=t&1):
//   P1: issue bqO(t);  STAGE B-h0(t+1); bar; lgkm(4);  QUAD(afE,bqE); bar
//   P2: issue afO(t);  STAGE A-h0(t+2); bar; lgkm(8);  QUAD(afE,bqO); bar
//   P3:                STAGE B-h1(t+2); bar; lgkm(0);  QUAD(afO,bqO); bar
//   P4:                STAGE A-h1(t+2); vmcnt(6); bar;
//       QUAD(afO,bqE-old); issue afE,bqE(t+1); bar
// Every LDS region's reads are count-waited + barrier-separated one phase
// before that region is re-staged (race-free); vmcnt(6) leaves exactly the
// 3 half-tiles of t+2 in flight.
// MODE: 0 = bf16 out; 1 = fp32 out + bias; 2 = bf16 exp(acc/64)->P + Lpart;
//       3 = bf16 acc/sum(Lpart) -> attnO scatter.
// ---------------------------------------------------------------------------
#define BARRIER() __builtin_amdgcn_s_barrier()
#define FENCE() asm volatile("" ::: "memory")
#define VMC6() asm volatile("s_waitcnt vmcnt(6)" ::: "memory")
#define LGKM(N)                                                   \
  do {                                                            \
    asm volatile("s_waitcnt lgkmcnt(" #N ")" ::: "memory");       \
    __builtin_amdgcn_sched_barrier(0);                            \
  } while (0)

#define LDA(AF, buf, mh)                                                      \
  do {                                                                        \
    _Pragma("unroll") for (int mi = 0; mi < 4; ++mi) {                        \
      int r = wm * 64 + mi * 16 + r16;                                        \
      _Pragma("unroll") for (int ks = 0; ks < 2; ++ks) {                      \
        int gg = ks * 4 + g;                                                  \
        AF[mi][ks] = *(const bf16x8*)(ldsB + (buf)*32768 + (mh)*16384 +       \
                                      r * 128 + ((gg ^ (r & 7)) << 4));       \
      }                                                                       \
    }                                                                         \
  } while (0)

#define LDB(BQ, buf, nh)                                                      \
  do {                                                                        \
    _Pragma("unroll") for (int ni = 0; ni < 2; ++ni) {                        \
      int r = wn * 32 + ni * 16 + r16;                                        \
      _Pragma("unroll") for (int ks = 0; ks < 2; ++ks) {                      \
        int gg = ks * 4 + g;                                                  \
        BQ[ni][ks] = *(const bf16x8*)(ldsB + 65536 + (buf)*32768 +            \
                                      (nh)*16384 + r * 128 +                  \
                                      ((gg ^ (r & 7)) << 4));                 \
      }                                                                       \
    }                                                                         \
  } while (0)

#define QUAD(AF, mh, nh, BQ)                                                  \
  do {                                                                        \
    __builtin_amdgcn_s_setprio(1);                                            \
    _Pragma("unroll") for (int ks = 0; ks < 2; ++ks)                          \
        _Pragma("unroll") for (int mi = 0; mi < 4; ++mi)                      \
            _Pragma("unroll") for (int ni = 0; ni < 2; ++ni)                  \
                acc[(mh)*4 + mi][(nh)*2 + ni] =                               \
                    MFMA16(AF[mi][ks], BQ[ni][ks],                            \
                           acc[(mh)*4 + mi][(nh)*2 + ni]);                    \
    __builtin_amdgcn_s_setprio(0);                                            \
    __builtin_amdgcn_sched_barrier(0);                                        \
  } while (0)

#define STAGE_A(mh, tau)                                                      \
  do {                                                                        \
    int tc = (tau) < NT ? (tau) : NT - 1;                                     \
    char* dbase = ldsB + ((tau)&1) * 32768 + (mh)*16384;                      \
    _Pragma("unroll") for (int i = 0; i < 2; ++i)                             \
        __builtin_amdgcn_global_load_lds(                                     \
            (const __attribute__((address_space(1))) void*)(Ap +              \
                offA[i][mh] + tc * 64),                                       \
            (__attribute__((address_space(3))) void*)(dbase +                 \
                (i * 512 + w * 64) * 16), 16, 0, 0);                          \
  } while (0)

#define STAGE_B(nh, tau)                                                      \
  do {                                                                        \
    int tc = (tau) < NT ? (tau) : NT - 1;                                     \
    char* dbase = ldsB + 65536 + ((tau)&1) * 32768 + (nh)*16384;              \
    _Pragma("unroll") for (int i = 0; i < 2; ++i)                             \
        __builtin_amdgcn_global_load_lds(                                     \
            (const __attribute__((address_space(1))) void*)(Bp +              \
                offB[i][nh] + tc * 64),                                       \
            (__attribute__((address_space(3))) void*)(dbase +                 \
                (i * 512 + w * 64) * 16), 16, 0, 0);                          \
  } while (0)

#define PIPELINE_LOOP()                                                       \
  STAGE_A(0, 0); STAGE_B(1, 0); STAGE_A(1, 0); STAGE_B(0, 0);                 \
  STAGE_A(0, 1); STAGE_B(1, 1); STAGE_A(1, 1);                                \
  VMC6();                                                                     \
  BARRIER();                                                                  \
  FENCE();                                                                    \
  LDA(afE, 0, 0);                                                             \
  LDB(bqE, 0, 0);                                                             \
  for (int t = 0; t < NT; ++t) {                                              \
    int buf = t & 1;                                                          \
    LDB(bqO, buf, 1);                                                         \
    STAGE_B(0, t + 1);                                                        \
    BARRIER();                                                                \
    LGKM(4);                                                                  \
    QUAD(afE, 0, 0, bqE);                                                     \
    BARRIER();                                                                \
    LDA(afO, buf, 1);                                                         \
    STAGE_A(0, t + 2);                                                        \
    BARRIER();                                                                \
    LGKM(8);                                                                  \
    QUAD(afE, 0, 1, bqO);                                                     \
    BARRIER();                                                                \
    STAGE_B(1, t + 2);                                                        \
    BARRIER();                                                                \
    LGKM(0);                                                                  \
    QUAD(afO, 1, 1, bqO);                                                     \
    BARRIER();                                                                \
    STAGE_A(1, t + 2);                                                        \
    VMC6();                                                                   \
    BARRIER();                                                                \
    FENCE();                                                                  \
    QUAD(afO, 1, 0, bqE);                                                     \
    LDA(afE, buf ^ 1, 0);                                                     \
    LDB(bqE, buf ^ 1, 0);                                                     \
    BARRIER();                                                                \
  }

#define SETUP_OFFSETS()                                                       \
  int offA[2][2], offB[2][2];                                                 \
  _Pragma("unroll") for (int i = 0; i < 2; ++i) {                             \
    int c = i * 512 + tid;                                                    \
    int r = c >> 3, slot = c & 7;                                             \
    int colsw = (slot ^ (r & 7)) << 3;                                        \
    _Pragma("unroll") for (int h = 0; h < 2; ++h) {                           \
      int RA = (r >> 6) * 128 + h * 64 + (r & 63);                            \
      int RB = (r >> 5) * 64 + h * 32 + (r & 31);                             \
      offA[i][h] = RA * lda + colsw;                                          \
      offB[i][h] = RB * ldb + colsw;                                          \
    }                                                                         \
  }

template <int MODE>
__global__ __launch_bounds__(512, 2) void k_gemm8(
    const __bf16* __restrict__ Abase, const __bf16* __restrict__ Bbase,
    void* __restrict__ Cout, const float* __restrict__ aux,
    int lda, int ldb, int N, int K) {
  __shared__ __align__(128) __bf16 lds[65536];  // 128 KiB
  char* ldsB = (char*)lds;
  int tid = threadIdx.x;
  int w = tid >> 6, lane = tid & 63;
  int r16 = lane & 15, g = lane >> 4;
  int wm = w >> 2, wn = w & 3;
  int z = blockIdx.z;

  int bx, by;
  if (MODE <= 1) {
    // 2D XCD rectangles (4x2), column-major walk within each rect.
    int gx = gridDim.x, gy = gridDim.y;
    int RX = gx >> 2, RY = gy >> 1;
    int orig = blockIdx.y * gx + blockIdx.x;
    int xcd = orig & 7, idx = orig >> 3;
    int lbx = idx / RY, lby = idx - lbx * RY;
    bx = (xcd & 3) * RX + lbx;
    by = (xcd >> 2) * RY + lby;
  } else {
    bx = blockIdx.x; by = blockIdx.y;
  }
  int m0 = by * 256, n0 = bx * 256;

  const __bf16 *Ap, *Bp;
  if (MODE == 2) {
    int b = z >> 3, h = z & 7;
    Ap = Abase + (size_t)b * 1024 * 12288 + h * 512;          // Q rows
    Bp = Abase + (size_t)b * 1024 * 12288 + 4096 + h * 512;   // K rows
  } else if (MODE == 3) {
    Ap = Abase + (size_t)z * 1048576;   // P[z]
    Bp = Bbase + (size_t)z * 524288;    // Vt[z]
  } else {
    Ap = Abase; Bp = Bbase;
  }
  Ap += (size_t)m0 * lda;
  Bp += (size_t)n0 * ldb;
  SETUP_OFFSETS()

  int NT = K >> 6;
  f32x4 acc[8][4];
#pragma unroll
  for (int a = 0; a < 8; ++a)
#pragma unroll
    for (int bq = 0; bq < 4; ++bq) acc[a][bq] = f32x4{0.f, 0.f, 0.f, 0.f};
  bf16x8 afE[4][2], afO[4][2], bqE[2][2], bqO[2][2];

  PIPELINE_LOOP()

  if (MODE == 2) {
    // drain staging DMA + dangling prefetch reads before reusing LDS
    asm volatile("s_waitcnt vmcnt(0)" ::: "memory");
    __syncthreads();
    float* Lbuf = (float*)ldsB;
#pragma unroll
    for (int mig = 0; mig < 8; ++mig) {
#pragma unroll
      for (int ii = 0; ii < 4; ++ii) {
        int row = m0 + wm * 128 + mig * 16 + g * 4 + ii;
        float s = 0.f;
#pragma unroll
        for (int nig = 0; nig < 4; ++nig) {
          int col = n0 + wn * 64 + nig * 16 + r16;
          float e = __expf(acc[mig][nig][ii] * 0.015625f);
          ((__bf16*)Cout)[(size_t)z * 1048576 + (size_t)row * 1024 + col] =
              (__bf16)e;
          s += e;
        }
        s += __shfl_xor(s, 1, 64);
        s += __shfl_xor(s, 2, 64);
        s += __shfl_xor(s, 4, 64);
        s += __shfl_xor(s, 8, 64);
        if (r16 == 0)
          Lbuf[(wm * 4 + wn) * 128 + mig * 16 + g * 4 + ii] = s;
      }
    }
    __syncthreads();
    if (tid < 256) {
      int wmi = tid >> 7, rl = tid & 127;
      const float* base = Lbuf + wmi * 512;
      float s = base[rl] + base[128 + rl] + base[256 + rl] + base[384 + rl];
      ((float*)aux)[z * 4096 + blockIdx.x * 1024 + m0 + tid] = s;
    }
    return;
  }

#pragma unroll
  for (int mig = 0; mig < 8; ++mig) {
#pragma unroll
    for (int ii = 0; ii < 4; ++ii) {
      int row = m0 + wm * 128 + mig * 16 + g * 4 + ii;
      float lval = 0.f;
      if (MODE == 3)
        lval = aux[z * 4096 + row] + aux[z * 4096 + 1024 + row] +
               aux[z * 4096 + 2048 + row] + aux[z * 4096 + 3072 + row];
#pragma unroll
      for (int nig = 0; nig < 4; ++nig) {
        int col = n0 + wn * 64 + nig * 16 + r16;
        float v = acc[mig][nig][ii];
        if (MODE == 0) {
          ((__bf16*)Cout)[(size_t)row * N + col] = (__bf16)v;
        } else if (MODE == 1) {
          ((float*)Cout)[(size_t)row * N + col] = v + aux[col];
        } else if (MODE == 3) {
          ((__bf16*)Cout)[(size_t)((z >> 3) * 1024 + row) * 4096 +
                          (z & 7) * 512 + col] = (__bf16)(v / lval);
        }
      }
    }
  }
}

// ---------------------------------------------------------------------------
// Orchestration. ws layout (268.4 MB):
//   [0,        33.5MB)  xb  (x bf16)  -> reused as attnO
//   [33.5MB,  134.2MB)  wT (WqkvT)    -> reused as P(64MB)+Lpart, then WoutT
//   [134.2MB, 234.9MB)  qkv
//   [234.9MB, 268.4MB)  vt
// ---------------------------------------------------------------------------
extern "C" void kernel_launch(void* const* d_in, const int* in_sizes, int n_in,
                              void* d_out, int out_size, void* d_ws, size_t ws_size,
                              hipStream_t stream) {
  const float* x = (const float*)d_in[0];
  const float* Wqkv = (const float*)d_in[1];
  const float* Wout = (const float*)d_in[2];
  const float* bout = (const float*)d_in[3];
  float* out = (float*)d_out;
  char* ws = (char*)d_ws;

  __bf16* xb = (__bf16*)(ws);
  __bf16* wT = (__bf16*)(ws + 33554432);
  __bf16* P = (__bf16*)(ws + 33554432);
  float* Lpart = (float*)(ws + 33554432 + 67108864);  // [32][4][1024]
  __bf16* qkv = (__bf16*)(ws + 134217728);
  __bf16* vt = (__bf16*)(ws + 234881024);

  k_conv<<<16384, 256, 0, stream>>>(x, xb, 4194304);
  k_transpose_f32_bf16<<<dim3(192, 64), 256, 0, stream>>>(Wqkv, wT, 4096, 12288);
  // qkv = xb @ Wqkv : M=4096 N=12288 K=4096 -> 48x16 blocks
  k_gemm8<0><<<dim3(48, 16), 512, 0, stream>>>(xb, wT, qkv, nullptr, 4096, 4096, 12288, 4096);
  k_transpose_v<<<dim3(8, 16, 32), 256, 0, stream>>>(qkv, vt);
  // P = exp(scale * Q K^T) + Lpart : per pair M=N=1024 K=512
  k_gemm8<2><<<dim3(4, 4, 32), 512, 0, stream>>>(qkv, qkv, P, Lpart, 12288, 12288, 1024, 512);
  // attnO = (P @ V) / L : per pair M=1024 N=512 K=1024
  k_gemm8<3><<<dim3(2, 4, 32), 512, 0, stream>>>(P, vt, xb, Lpart, 1024, 1024, 512, 1024);
  k_transpose_f32_bf16<<<dim3(64, 64), 256, 0, stream>>>(Wout, wT, 4096, 4096);
  // out = attnO @ Wout + bout : M=N=4096 K=4096 -> 16x16 blocks
  k_gemm8<1><<<dim3(16, 16), 512, 0, stream>>>(xb, wT, out, bout, 4096, 4096, 4096, 4096);
}